// Round 9
// baseline (133.616 us; speedup 1.0000x reference)
//
#include <hip/hip_runtime.h>
#include <hip/hip_bf16.h>
#include <math.h>

#define D 1280
#define NST 20
#define MTRI 190
#define NTOK 8192   // B*L
#define NC 256      // padded logit columns

typedef __attribute__((ext_vector_type(4))) float f32x4;
typedef __attribute__((ext_vector_type(8))) __bf16 bf16x8;
typedef __attribute__((ext_vector_type(8))) unsigned short ushort8;
typedef __attribute__((ext_vector_type(4))) unsigned short bfu4;

__device__ __forceinline__ void gload_lds16(const void* g, void* l) {
    __builtin_amdgcn_global_load_lds(
        (const __attribute__((address_space(1))) void*)g,
        (__attribute__((address_space(3))) void*)l, 16, 0, 0);
}

__device__ __forceinline__ unsigned short f2bf(float x) {
    __hip_bfloat16 b = __float2bfloat16(x);
    return __builtin_bit_cast(unsigned short, b);
}
__device__ __forceinline__ float bf2f(unsigned short u) {
    unsigned int x = ((unsigned int)u) << 16;
    return __builtin_bit_cast(float, x);
}

// ---------- Kernel P0: hx f32 -> bf16 ----------
__global__ __launch_bounds__(256) void tobf_kernel(
    const float* __restrict__ X, unsigned short* __restrict__ Y)
{
    const size_t i = ((size_t)blockIdx.x * 256 + threadIdx.x) * 8;
    float4 a = *(const float4*)(X + i);
    float4 b = *(const float4*)(X + i + 4);
    ushort8 u;
    u[0] = f2bf(a.x); u[1] = f2bf(a.y); u[2] = f2bf(a.z); u[3] = f2bf(a.w);
    u[4] = f2bf(b.x); u[5] = f2bf(b.y); u[6] = f2bf(b.z); u[7] = f2bf(b.w);
    *(ushort8*)(Y + i) = u;
}

// ---------- Kernel P1: Wt[n][k] = bf16(dense_w[k][n]) ----------
__global__ __launch_bounds__(256) void transpose_w_kernel(
    const float* __restrict__ W, unsigned short* __restrict__ Wt)
{
    __shared__ float t[64][65];
    const int tid = threadIdx.x;
    const int k0 = blockIdx.x * 64, n0 = blockIdx.y * 64;
#pragma unroll
    for (int i = 0; i < 16; ++i) {
        int lin = i * 256 + tid;
        int r = lin >> 6, c = lin & 63;
        t[r][c] = W[(size_t)(k0 + r) * D + n0 + c];
    }
    __syncthreads();
#pragma unroll
    for (int i = 0; i < 16; ++i) {
        int lin = i * 256 + tid;
        int r = lin >> 6, c = lin & 63;
        Wt[(size_t)(n0 + r) * D + (k0 + c)] = f2bf(t[c][r]);
    }
}

// ---------- Kernel P2: Wcat[col][k] ----------
__global__ __launch_bounds__(256) void build_wcat_kernel(
    const float* __restrict__ theta_w, const float* __restrict__ Theta_w,
    unsigned short* __restrict__ Wcat)
{
    const int col = threadIdx.x;          // 0..255
    const int k0  = blockIdx.x * 64;      // 20 blocks
    for (int kk = 0; kk < 64; kk += 8) {
        ushort8 u;
#pragma unroll
        for (int j = 0; j < 8; ++j) {
            int k = k0 + kk + j;
            float v = 0.0f;
            if (col < NST)             v = theta_w[(size_t)k * NST + col];
            else if (col < NST + MTRI) v = Theta_w[(size_t)k * MTRI + (col - NST)];
            u[j] = f2bf(v);
        }
        *(ushort8*)&Wcat[(size_t)col * D + k0 + kk] = u;
    }
}

// ---------- Kernel A: H = gelu(hxb @ dense_w + b), 128x64 tile ----------
// NBUF=2 (24 KB LDS, ~6 blocks/CU) + counted vmcnt(3) + TWO barriers/iter:
//   [STAGE(t+1); vmcnt(3); bar; COMPUTE(t); bar]
// bar1+own-vmcnt => RAW safe (all waves' stage(t) landed before reads);
// bar2 => WAR safe (reads of buf X end before next iter's writes to X).
#define BKA 32
#define KITERS (D / BKA)   // 40

__global__ __launch_bounds__(256) void gemm_gelu_mfma_kernel(
    const unsigned short* __restrict__ Ab,  // [NTOK, D] bf16
    const unsigned short* __restrict__ Wt,  // [D(n), D(k)] bf16
    const float* __restrict__ bias,
    unsigned short* __restrict__ H)         // [NTOK, D] bf16
{
    __shared__ unsigned short As[2][128 * BKA];  // 2 x 8 KB
    __shared__ unsigned short Bs[2][64 * BKA];   // 2 x 4 KB

    const int tid  = threadIdx.x;
    const int lane = tid & 63;
    const int w    = tid >> 6;
    const int wr   = w >> 1;        // 0..1: 64-row half
    const int wc   = w & 1;         // 0..1: 32-col half

    // XCD-bijective swizzle: 1280 blocks = 8 x 160
    const int bid = blockIdx.x;
    const int swz = (bid & 7) * 160 + (bid >> 3);
    const int row0 = (swz / 20) * 128;   // 64 row tiles
    const int col0 = (swz % 20) * 64;    // 20 col tiles

    f32x4 acc[4][2];
#pragma unroll
    for (int m = 0; m < 4; ++m)
#pragma unroll
        for (int n = 0; n < 2; ++n) acc[m][n] = (f32x4)0.0f;

    // staging: each issue covers 16 rows x 32 k.
    // lane -> row r16 = lane>>2; k-slot pre-swizzled: (lane&3) ^ ((r16>>1)&3)
    const int sR = lane >> 2;
    const int sK = ((lane & 3) ^ ((sR >> 1) & 3)) * 8;
    const unsigned short* aSrc = &Ab[(size_t)(row0 + w * 16 + sR) * D + sK];
    const unsigned short* bSrc = &Wt[(size_t)(col0 + w * 16 + sR) * D + sK];

    auto STAGE = [&](int b, int kt) {
        const int k0 = kt * BKA;
#pragma unroll
        for (int p = 0; p < 2; ++p)
            gload_lds16(aSrc + (size_t)(p * 64) * D + k0,
                        &As[b][(p * 64 + w * 16) * BKA]);
        gload_lds16(bSrc + k0, &Bs[b][(w * 16) * BKA]);
    };

    // fragment read: swizzled k-slot (same XOR as write side)
    const int fr = lane & 15;
    const int fk = (((lane >> 4) ^ ((fr >> 1) & 3))) * 8;

    auto COMPUTE = [&](int cur) {
        bf16x8 af[4], bfv[2];
#pragma unroll
        for (int m = 0; m < 4; ++m)
            af[m] = *(const bf16x8*)&As[cur][(wr * 64 + m * 16 + fr) * BKA + fk];
#pragma unroll
        for (int n = 0; n < 2; ++n)
            bfv[n] = *(const bf16x8*)&Bs[cur][(wc * 32 + n * 16 + fr) * BKA + fk];
#pragma unroll
        for (int m = 0; m < 4; ++m)
#pragma unroll
            for (int n = 0; n < 2; ++n)
                acc[m][n] = __builtin_amdgcn_mfma_f32_16x16x32_bf16(
                    af[m], bfv[n], acc[m][n], 0, 0, 0);
    };

    STAGE(0, 0);

    for (int t = 0; t < KITERS - 1; ++t) {
        STAGE((t + 1) & 1, t + 1);
        asm volatile("s_waitcnt vmcnt(3)" ::: "memory");
        __builtin_amdgcn_s_barrier();
        asm volatile("" ::: "memory");
        COMPUTE(t & 1);
        asm volatile("" ::: "memory");
        __builtin_amdgcn_s_barrier();   // WAR fence: reads done before next writes
    }
    asm volatile("s_waitcnt vmcnt(0)" ::: "memory");
    __builtin_amdgcn_s_barrier();
    asm volatile("" ::: "memory");
    COMPUTE((KITERS - 1) & 1);

    const int crow = (lane >> 4) * 4;
#pragma unroll
    for (int n = 0; n < 2; ++n) {
        const int col = col0 + wc * 32 + n * 16 + fr;
        const float bv = bias[col];
#pragma unroll
        for (int m = 0; m < 4; ++m) {
            const int rbase = row0 + wr * 64 + m * 16 + crow;
#pragma unroll
            for (int r = 0; r < 4; ++r) {
                float h = acc[m][n][r] + bv;
                float g = 0.5f * h * (1.0f + erff(h * 0.70710678118654752f));
                H[(size_t)(rbase + r) * D + col] = f2bf(g);
            }
        }
    }
}

// ---------- Kernel S: per-row LN stats (mean, rstd) ----------
__global__ __launch_bounds__(256) void ln_stats_kernel(
    const unsigned short* __restrict__ Hb, float2* __restrict__ stats)
{
    const int wave = threadIdx.x >> 6, lane = threadIdx.x & 63;
    const int row = blockIdx.x * 4 + wave;
    const unsigned short* src = Hb + (size_t)row * D;
    float sum = 0.f, sq = 0.f;
#pragma unroll
    for (int i = 0; i < 5; ++i) {
        bfu4 u = *(const bfu4*)(src + (size_t)(i * 64 + lane) * 4);
#pragma unroll
        for (int j = 0; j < 4; ++j) {
            float f = bf2f(u[j]);
            sum += f; sq += f * f;
        }
    }
#pragma unroll
    for (int off = 1; off < 64; off <<= 1) {
        sum += __shfl_xor(sum, off);
        sq  += __shfl_xor(sq, off);
    }
    if (lane == 0) {
        float mean = sum * (1.0f / D);
        float var  = sq * (1.0f / D) - mean * mean;
        stats[row] = make_float2(mean, rsqrtf(var + 1e-5f));
    }
}

// ---------- Kernel C: fused LN-apply + logits MFMA + softmax/softplus + Q ----
// 16 rows/block, 512 blocks, 4 waves, 2-phase dbuf (__syncthreads structure).
__global__ __launch_bounds__(256) void head_mfma_kernel(
    const unsigned short* __restrict__ Hb,
    const float2* __restrict__ stats,
    const float* __restrict__ ln_w, const float* __restrict__ ln_b,
    const float* __restrict__ theta_b, const float* __restrict__ Theta_b,
    const unsigned short* __restrict__ Wcat,
    float* __restrict__ Out)
{
    __shared__ unsigned short Bs[2][NC * 32];   // 2 x 16 KB
    __shared__ unsigned short As[2][16 * 32];   // 2 x 1 KB
    __shared__ float lnw_s[D], lnb_s[D];        // 10 KB
    __shared__ float biascat[NC];               // 1 KB
    __shared__ float mean_s[16], inv_s[16];
    // post-GEMM arrays alias Bs[0] (14.4 KB <= 16 KB)
    float (*th_l)[NST]  = (float (*)[NST])&Bs[0][0];
    float (*sp_l)[MTRI] = (float (*)[MTRI])((char*)&Bs[0][0] + 16 * NST * 4);
    float (*s_l)[NST]   = (float (*)[NST])((char*)&Bs[0][0] + 16 * NST * 4 + 16 * MTRI * 4);

    const int tid  = threadIdx.x;
    const int lane = tid & 63;
    const int wave = tid >> 6;
    const int bid  = blockIdx.x;
    const int swz  = (bid & 7) * 64 + (bid >> 3);   // 512 = 8 x 64
    const int g0   = swz * 16;

#pragma unroll
    for (int i = 0; i < 5; ++i) {
        int k = i * 256 + tid;
        lnw_s[k] = ln_w[k];
        lnb_s[k] = ln_b[k];
    }
    {
        float v = 0.0f;
        if (tid < NST) v = theta_b[tid];
        else if (tid < NST + MTRI) v = Theta_b[tid - NST];
        biascat[tid] = v;
    }
    if (tid < 16) {
        float2 s = stats[g0 + tid];
        mean_s[tid] = s.x;
        inv_s[tid]  = s.y;
    }
    __syncthreads();

    auto STAGEB = [&](int b, int k0) {
#pragma unroll
        for (int i = 0; i < 4; ++i) {
            const int c0 = wave * 64 + i * 16;
            gload_lds16(&Wcat[(size_t)(c0 + (lane >> 2)) * D + k0 + (lane & 3) * 8],
                        &Bs[b][c0 * 32]);
        }
    };
    auto STAGEA = [&](int b, int k0) {
        if (lane < 16) {
            const int row = wave * 4 + (lane >> 2);
            const int k8  = (lane & 3) * 8;
            const float mean = mean_s[row], inv = inv_s[row];
            ushort8 u = *(const ushort8*)(Hb + (size_t)(g0 + row) * D + k0 + k8);
            ushort8 o;
#pragma unroll
            for (int j = 0; j < 8; ++j) {
                int k = k0 + k8 + j;
                o[j] = f2bf((bf2f(u[j]) - mean) * inv * lnw_s[k] + lnb_s[k]);
            }
            *(ushort8*)&As[b][row * 32 + k8] = o;
        }
    };

    STAGEB(0, 0);
    STAGEA(0, 0);
    __syncthreads();

    f32x4 acc[4];
#pragma unroll
    for (int n = 0; n < 4; ++n) acc[n] = (f32x4)0.0f;

    const int fr = lane & 15;
    const int fk = (lane >> 4) * 8;

    for (int t = 0; t < 40; ++t) {
        const int cur = t & 1;
        if (t < 39) {
            STAGEB(cur ^ 1, (t + 1) * 32);
            STAGEA(cur ^ 1, (t + 1) * 32);
        }
        bf16x8 af = *(const bf16x8*)&As[cur][fr * 32 + fk];
#pragma unroll
        for (int n = 0; n < 4; ++n) {
            bf16x8 bfv = *(const bf16x8*)&Bs[cur][(wave * 64 + n * 16 + fr) * 32 + fk];
            acc[n] = __builtin_amdgcn_mfma_f32_16x16x32_bf16(af, bfv, acc[n], 0, 0, 0);
        }
        __syncthreads();
    }

    // ---- logits -> th_l / softplus(sp_l) ----
    const int crow = (lane >> 4) * 4;
#pragma unroll
    for (int n = 0; n < 4; ++n) {
        const int col = wave * 64 + n * 16 + fr;
        const float bv = biascat[col];
#pragma unroll
        for (int r = 0; r < 4; ++r) {
            const int row = crow + r;
            float v = acc[n][r] + bv;
            if (col < NST) {
                th_l[row][col] = v;
            } else if (col < NST + MTRI) {
                sp_l[row][col - NST] = (v > 20.0f) ? v : log1pf(expf(v));
            }
        }
    }
    __syncthreads();

    // ---- softmax -> sqrt(pi): half-wave per row ----
#pragma unroll
    for (int p = 0; p < 2; ++p) {
        const int r = p * 8 + wave * 2 + (lane >> 5);
        const int l = lane & 31;
        float v = (l < NST) ? th_l[r][l] : -1e30f;
        float m = v;
#pragma unroll
        for (int off = 16; off >= 1; off >>= 1) m = fmaxf(m, __shfl_xor(m, off));
        float e = (l < NST) ? __expf(v - m) : 0.0f;
        float s = e;
#pragma unroll
        for (int off = 16; off >= 1; off >>= 1) s += __shfl_xor(s, off);
        if (l < NST) s_l[r][l] = sqrtf(e / s);
    }
    __syncthreads();

    // ---- Q assembly: 320 (row,i) pairs ----
#pragma unroll
    for (int base = 0; base < 320; base += 256) {
        const int idx = base + tid;
        if (idx < 320) {
            const int r = idx / NST;
            const int i = idx % NST;
            const float inv_si = 1.0f / s_l[r][i];
            float q[NST];
            float rowsum = 0.f;
#pragma unroll
            for (int j = 0; j < NST; ++j) {
                if (j == i) { q[j] = 0.f; continue; }
                int a = (i < j) ? i : j;
                int b = (i < j) ? j : i;
                int tix = a * NST - a * (a + 1) / 2 + (b - a - 1);
                float v = sp_l[r][tix] * s_l[r][j] * inv_si;
                q[j] = v;
                rowsum += v;
            }
            q[i] = -rowsum;
            float* dst = Out + (size_t)(g0 + r) * (NST * NST) + i * NST;
#pragma unroll
            for (int j4 = 0; j4 < 5; ++j4) {
                *(float4*)(dst + j4 * 4) =
                    make_float4(q[j4 * 4], q[j4 * 4 + 1], q[j4 * 4 + 2], q[j4 * 4 + 3]);
            }
        }
    }
}

extern "C" void kernel_launch(void* const* d_in, const int* in_sizes, int n_in,
                              void* d_out, int out_size, void* d_ws, size_t ws_size,
                              hipStream_t stream) {
    const float* hx      = (const float*)d_in[0];
    const float* dense_w = (const float*)d_in[1];
    const float* dense_b = (const float*)d_in[2];
    const float* ln_w    = (const float*)d_in[3];
    const float* ln_b    = (const float*)d_in[4];
    const float* theta_w = (const float*)d_in[5];
    const float* theta_b = (const float*)d_in[6];
    const float* Theta_w = (const float*)d_in[7];
    const float* Theta_b = (const float*)d_in[8];
    float* out = (float*)d_out;

    // ws: hxb bf16 21MB | H bf16 21MB | Wt bf16 3.3MB | Wcat bf16 0.66MB
    // stats (64KB) reuses hxb region (dead after GEMM A)
    unsigned short* hxb  = (unsigned short*)d_ws;
    unsigned short* H    = hxb + (size_t)NTOK * D;
    unsigned short* Wt   = H + (size_t)NTOK * D;
    unsigned short* Wcat = Wt + (size_t)D * D;
    float2* stats        = (float2*)d_ws;

    tobf_kernel<<<(NTOK * D) / 2048, 256, 0, stream>>>(hx, hxb);

    dim3 gridT(D / 64, D / 64);
    transpose_w_kernel<<<gridT, 256, 0, stream>>>(dense_w, Wt);
    build_wcat_kernel<<<D / 64, 256, 0, stream>>>(theta_w, Theta_w, Wcat);

    gemm_gelu_mfma_kernel<<<1280, 256, 0, stream>>>(hxb, Wt, dense_b, H);

    ln_stats_kernel<<<NTOK / 4, 256, 0, stream>>>(H, stats);

    head_mfma_kernel<<<512, 256, 0, stream>>>(H, stats, ln_w, ln_b, theta_b,
                                              Theta_b, Wcat, out);
}

// Round 10
// 126.091 us; speedup vs baseline: 1.0597x; 1.0597x over previous
//
#include <hip/hip_runtime.h>
#include <hip/hip_bf16.h>
#include <math.h>

#define D 1280
#define NST 20
#define MTRI 190
#define NTOK 8192   // B*L
#define NC 256      // padded logit columns

typedef __attribute__((ext_vector_type(4))) float f32x4;
typedef __attribute__((ext_vector_type(8))) __bf16 bf16x8;
typedef __attribute__((ext_vector_type(8))) unsigned short ushort8;

__device__ __forceinline__ void gload_lds16(const void* g, void* l) {
    __builtin_amdgcn_global_load_lds(
        (const __attribute__((address_space(1))) void*)g,
        (__attribute__((address_space(3))) void*)l, 16, 0, 0);
}

__device__ __forceinline__ unsigned short f2bf(float x) {
    __hip_bfloat16 b = __float2bfloat16(x);
    return __builtin_bit_cast(unsigned short, b);
}
__device__ __forceinline__ float bf2f(unsigned short u) {
    unsigned int x = ((unsigned int)u) << 16;
    return __builtin_bit_cast(float, x);
}

// ---------- Kernel P0: hx f32 -> bf16 ----------
__global__ __launch_bounds__(256) void tobf_kernel(
    const float* __restrict__ X, unsigned short* __restrict__ Y)
{
    const size_t i = ((size_t)blockIdx.x * 256 + threadIdx.x) * 8;
    float4 a = *(const float4*)(X + i);
    float4 b = *(const float4*)(X + i + 4);
    ushort8 u;
    u[0] = f2bf(a.x); u[1] = f2bf(a.y); u[2] = f2bf(a.z); u[3] = f2bf(a.w);
    u[4] = f2bf(b.x); u[5] = f2bf(b.y); u[6] = f2bf(b.z); u[7] = f2bf(b.w);
    *(ushort8*)(Y + i) = u;
}

// ---------- Kernel P1: Wt[n][k] = bf16(dense_w[k][n]) ----------
__global__ __launch_bounds__(256) void transpose_w_kernel(
    const float* __restrict__ W, unsigned short* __restrict__ Wt)
{
    __shared__ float t[64][65];
    const int tid = threadIdx.x;
    const int k0 = blockIdx.x * 64, n0 = blockIdx.y * 64;
#pragma unroll
    for (int i = 0; i < 16; ++i) {
        int lin = i * 256 + tid;
        int r = lin >> 6, c = lin & 63;
        t[r][c] = W[(size_t)(k0 + r) * D + n0 + c];
    }
    __syncthreads();
#pragma unroll
    for (int i = 0; i < 16; ++i) {
        int lin = i * 256 + tid;
        int r = lin >> 6, c = lin & 63;
        Wt[(size_t)(n0 + r) * D + (k0 + c)] = f2bf(t[c][r]);
    }
}

// ---------- Kernel P2: Wcat[col][k] ----------
__global__ __launch_bounds__(256) void build_wcat_kernel(
    const float* __restrict__ theta_w, const float* __restrict__ Theta_w,
    unsigned short* __restrict__ Wcat)
{
    const int col = threadIdx.x;          // 0..255
    const int k0  = blockIdx.x * 64;      // 20 blocks
    for (int kk = 0; kk < 64; kk += 8) {
        ushort8 u;
#pragma unroll
        for (int j = 0; j < 8; ++j) {
            int k = k0 + kk + j;
            float v = 0.0f;
            if (col < NST)             v = theta_w[(size_t)k * NST + col];
            else if (col < NST + MTRI) v = Theta_w[(size_t)k * MTRI + (col - NST)];
            u[j] = f2bf(v);
        }
        *(ushort8*)&Wcat[(size_t)col * D + k0 + kk] = u;
    }
}

// ---------- Kernel A: H = gelu(hxb @ dense_w + b), 128x64 tile, dbuf ----------
// EXACT R5 structure (known-good 80us): NBUF=2, __syncthreads per iter,
// plain linear LDS, 1280 blocks (5/CU) for L2 panel co-residency.
#define BKA 32

__global__ __launch_bounds__(256) void gemm_gelu_mfma_kernel(
    const unsigned short* __restrict__ Ab,  // [NTOK, D] bf16
    const unsigned short* __restrict__ Wt,  // [D(n), D(k)] bf16
    const float* __restrict__ bias,
    unsigned short* __restrict__ H)         // [NTOK, D] bf16
{
    __shared__ unsigned short As[2][128 * BKA];  // 2 x 8 KB
    __shared__ unsigned short Bs[2][64 * BKA];   // 2 x 4 KB

    const int tid  = threadIdx.x;
    const int lane = tid & 63;
    const int w    = tid >> 6;
    const int wr   = w >> 1;        // 0..1: 64-row half
    const int wc   = w & 1;         // 0..1: 32-col half

    // XCD-bijective swizzle: 1280 blocks = 8 x 160
    const int bid = blockIdx.x;
    const int swz = (bid & 7) * 160 + (bid >> 3);
    const int row0 = (swz / 20) * 128;   // 64 row tiles
    const int col0 = (swz % 20) * 64;    // 20 col tiles

    f32x4 acc[4][2];
#pragma unroll
    for (int m = 0; m < 4; ++m)
#pragma unroll
        for (int n = 0; n < 2; ++n) acc[m][n] = (f32x4)0.0f;

    // staging: each issue covers 16 rows x 32 k; lane -> row (l>>2), k (l&3)*8
    const int sR = lane >> 2;
    const int sK = (lane & 3) * 8;
    const unsigned short* aSrc = &Ab[(size_t)(row0 + w * 16 + sR) * D + sK];
    const unsigned short* bSrc = &Wt[(size_t)(col0 + w * 16 + sR) * D + sK];

    auto STAGE = [&](int b, int k0) {
#pragma unroll
        for (int p = 0; p < 2; ++p)
            gload_lds16(aSrc + (size_t)(p * 64) * D + k0, &As[b][(p * 64 + w * 16) * BKA]);
        gload_lds16(bSrc + k0, &Bs[b][(w * 16) * BKA]);
    };

    STAGE(0, 0);
    __syncthreads();

    const int fr = lane & 15;
    const int fk = (lane >> 4) * 8;

    for (int t = 0; t < 40; ++t) {
        const int cur = t & 1;
        if (t < 39) STAGE(cur ^ 1, (t + 1) * BKA);

        bf16x8 af[4], bfv[2];
#pragma unroll
        for (int m = 0; m < 4; ++m)
            af[m] = *(const bf16x8*)&As[cur][(wr * 64 + m * 16 + fr) * BKA + fk];
#pragma unroll
        for (int n = 0; n < 2; ++n)
            bfv[n] = *(const bf16x8*)&Bs[cur][(wc * 32 + n * 16 + fr) * BKA + fk];
#pragma unroll
        for (int m = 0; m < 4; ++m)
#pragma unroll
            for (int n = 0; n < 2; ++n)
                acc[m][n] = __builtin_amdgcn_mfma_f32_16x16x32_bf16(
                    af[m], bfv[n], acc[m][n], 0, 0, 0);
        __syncthreads();
    }

    const int crow = (lane >> 4) * 4;
#pragma unroll
    for (int n = 0; n < 2; ++n) {
        const int col = col0 + wc * 32 + n * 16 + fr;
        const float bv = bias[col];
#pragma unroll
        for (int m = 0; m < 4; ++m) {
            const int rbase = row0 + wr * 64 + m * 16 + crow;
#pragma unroll
            for (int r = 0; r < 4; ++r) {
                float h = acc[m][n][r] + bv;
                float g = 0.5f * h * (1.0f + erff(h * 0.70710678118654752f));
                H[(size_t)(rbase + r) * D + col] = f2bf(g);
            }
        }
    }
}

// ---------- Kernel C: fused LN(stats+apply) + logits MFMA + softmax/softplus + Q
// 16 rows/block, 512 blocks, 4 waves, 2-phase dbuf. Stats computed in pass-1.
__global__ __launch_bounds__(256) void head_mfma_kernel(
    const unsigned short* __restrict__ Hb,
    const float* __restrict__ ln_w, const float* __restrict__ ln_b,
    const float* __restrict__ theta_b, const float* __restrict__ Theta_b,
    const unsigned short* __restrict__ Wcat,
    float* __restrict__ Out)
{
    __shared__ unsigned short Bs[2][NC * 32];   // 2 x 16 KB
    __shared__ unsigned short As[2][16 * 32];   // 2 x 1 KB
    __shared__ float lnw_s[D], lnb_s[D];        // 10 KB
    __shared__ float biascat[NC];               // 1 KB
    __shared__ float mean_s[16], inv_s[16];
    // post-GEMM arrays alias Bs[0] (14.4 KB <= 16 KB)
    float (*th_l)[NST]  = (float (*)[NST])&Bs[0][0];
    float (*sp_l)[MTRI] = (float (*)[MTRI])((char*)&Bs[0][0] + 16 * NST * 4);
    float (*s_l)[NST]   = (float (*)[NST])((char*)&Bs[0][0] + 16 * NST * 4 + 16 * MTRI * 4);

    const int tid  = threadIdx.x;
    const int lane = tid & 63;
    const int wave = tid >> 6;
    const int bid  = blockIdx.x;
    const int swz  = (bid & 7) * 64 + (bid >> 3);   // 512 = 8 x 64
    const int g0   = swz * 16;

#pragma unroll
    for (int i = 0; i < 5; ++i) {
        int k = i * 256 + tid;
        lnw_s[k] = ln_w[k];
        lnb_s[k] = ln_b[k];
    }
    {
        float v = 0.0f;
        if (tid < NST) v = theta_b[tid];
        else if (tid < NST + MTRI) v = Theta_b[tid - NST];
        biascat[tid] = v;
    }

    // ---- pass 1: LN stats, 4 rows per wave (wave-shuffle reduce) ----
#pragma unroll
    for (int rr = 0; rr < 4; ++rr) {
        const int r = wave * 4 + rr;
        const unsigned short* src = Hb + (size_t)(g0 + r) * D;
        float sum = 0.f, sq = 0.f;
#pragma unroll
        for (int it = 0; it < 3; ++it) {
            int c = it * 64 + lane;
            if (c < 160) {
                ushort8 u = *(const ushort8*)(src + c * 8);
#pragma unroll
                for (int j = 0; j < 8; ++j) {
                    float f = bf2f(u[j]);
                    sum += f; sq += f * f;
                }
            }
        }
#pragma unroll
        for (int off = 1; off < 64; off <<= 1) {
            sum += __shfl_xor(sum, off);
            sq  += __shfl_xor(sq, off);
        }
        if (lane == 0) {
            float mean = sum * (1.0f / D);
            float var  = sq * (1.0f / D) - mean * mean;
            mean_s[r] = mean;
            inv_s[r]  = rsqrtf(var + 1e-5f);
        }
    }
    __syncthreads();

    auto STAGEB = [&](int b, int k0) {
#pragma unroll
        for (int i = 0; i < 4; ++i) {
            const int c0 = wave * 64 + i * 16;
            gload_lds16(&Wcat[(size_t)(c0 + (lane >> 2)) * D + k0 + (lane & 3) * 8],
                        &Bs[b][c0 * 32]);
        }
    };
    auto STAGEA = [&](int b, int k0) {
        if (lane < 16) {
            const int row = wave * 4 + (lane >> 2);
            const int k8  = (lane & 3) * 8;
            const float mean = mean_s[row], inv = inv_s[row];
            ushort8 u = *(const ushort8*)(Hb + (size_t)(g0 + row) * D + k0 + k8);
            ushort8 o;
#pragma unroll
            for (int j = 0; j < 8; ++j) {
                int k = k0 + k8 + j;
                o[j] = f2bf((bf2f(u[j]) - mean) * inv * lnw_s[k] + lnb_s[k]);
            }
            *(ushort8*)&As[b][row * 32 + k8] = o;
        }
    };

    STAGEB(0, 0);
    STAGEA(0, 0);
    __syncthreads();

    f32x4 acc[4];
#pragma unroll
    for (int n = 0; n < 4; ++n) acc[n] = (f32x4)0.0f;

    const int fr = lane & 15;
    const int fk = (lane >> 4) * 8;

    for (int t = 0; t < 40; ++t) {
        const int cur = t & 1;
        if (t < 39) {
            STAGEB(cur ^ 1, (t + 1) * 32);
            STAGEA(cur ^ 1, (t + 1) * 32);
        }
        bf16x8 af = *(const bf16x8*)&As[cur][fr * 32 + fk];
#pragma unroll
        for (int n = 0; n < 4; ++n) {
            bf16x8 bfv = *(const bf16x8*)&Bs[cur][(wave * 64 + n * 16 + fr) * 32 + fk];
            acc[n] = __builtin_amdgcn_mfma_f32_16x16x32_bf16(af, bfv, acc[n], 0, 0, 0);
        }
        __syncthreads();
    }

    // ---- logits -> th_l / softplus(sp_l) ----
    const int crow = (lane >> 4) * 4;
#pragma unroll
    for (int n = 0; n < 4; ++n) {
        const int col = wave * 64 + n * 16 + fr;
        const float bv = biascat[col];
#pragma unroll
        for (int r = 0; r < 4; ++r) {
            const int row = crow + r;
            float v = acc[n][r] + bv;
            if (col < NST) {
                th_l[row][col] = v;
            } else if (col < NST + MTRI) {
                sp_l[row][col - NST] = (v > 20.0f) ? v : log1pf(expf(v));
            }
        }
    }
    __syncthreads();

    // ---- softmax -> sqrt(pi): half-wave per row ----
#pragma unroll
    for (int p = 0; p < 2; ++p) {
        const int r = p * 8 + wave * 2 + (lane >> 5);
        const int l = lane & 31;
        float v = (l < NST) ? th_l[r][l] : -1e30f;
        float m = v;
#pragma unroll
        for (int off = 16; off >= 1; off >>= 1) m = fmaxf(m, __shfl_xor(m, off));
        float e = (l < NST) ? __expf(v - m) : 0.0f;
        float s = e;
#pragma unroll
        for (int off = 16; off >= 1; off >>= 1) s += __shfl_xor(s, off);
        if (l < NST) s_l[r][l] = sqrtf(e / s);
    }
    __syncthreads();

    // ---- Q assembly: 320 (row,i) pairs ----
#pragma unroll
    for (int base = 0; base < 320; base += 256) {
        const int idx = base + tid;
        if (idx < 320) {
            const int r = idx / NST;
            const int i = idx % NST;
            const float inv_si = 1.0f / s_l[r][i];
            float q[NST];
            float rowsum = 0.f;
#pragma unroll
            for (int j = 0; j < NST; ++j) {
                if (j == i) { q[j] = 0.f; continue; }
                int a = (i < j) ? i : j;
                int b = (i < j) ? j : i;
                int tix = a * NST - a * (a + 1) / 2 + (b - a - 1);
                float v = sp_l[r][tix] * s_l[r][j] * inv_si;
                q[j] = v;
                rowsum += v;
            }
            q[i] = -rowsum;
            float* dst = Out + (size_t)(g0 + r) * (NST * NST) + i * NST;
#pragma unroll
            for (int j4 = 0; j4 < 5; ++j4) {
                *(float4*)(dst + j4 * 4) =
                    make_float4(q[j4 * 4], q[j4 * 4 + 1], q[j4 * 4 + 2], q[j4 * 4 + 3]);
            }
        }
    }
}

extern "C" void kernel_launch(void* const* d_in, const int* in_sizes, int n_in,
                              void* d_out, int out_size, void* d_ws, size_t ws_size,
                              hipStream_t stream) {
    const float* hx      = (const float*)d_in[0];
    const float* dense_w = (const float*)d_in[1];
    const float* dense_b = (const float*)d_in[2];
    const float* ln_w    = (const float*)d_in[3];
    const float* ln_b    = (const float*)d_in[4];
    const float* theta_w = (const float*)d_in[5];
    const float* theta_b = (const float*)d_in[6];
    const float* Theta_w = (const float*)d_in[7];
    const float* Theta_b = (const float*)d_in[8];
    float* out = (float*)d_out;

    // ws: hxb bf16 21MB | H bf16 21MB | Wt bf16 3.3MB | Wcat bf16 0.66MB
    unsigned short* hxb  = (unsigned short*)d_ws;
    unsigned short* H    = hxb + (size_t)NTOK * D;
    unsigned short* Wt   = H + (size_t)NTOK * D;
    unsigned short* Wcat = Wt + (size_t)D * D;

    tobf_kernel<<<(NTOK * D) / 2048, 256, 0, stream>>>(hx, hxb);

    dim3 gridT(D / 64, D / 64);
    transpose_w_kernel<<<gridT, 256, 0, stream>>>(dense_w, Wt);
    build_wcat_kernel<<<D / 64, 256, 0, stream>>>(theta_w, Theta_w, Wcat);

    gemm_gelu_mfma_kernel<<<1280, 256, 0, stream>>>(hxb, Wt, dense_b, H);

    head_mfma_kernel<<<512, 256, 0, stream>>>(H, ln_w, ln_b, theta_b,
                                              Theta_b, Wcat, out);
}